// Round 8
// baseline (254.703 us; speedup 1.0000x reference)
//
#include <hip/hip_runtime.h>
#include <cstdint>
#include <cstddef>

#define F_IN 256
#define F_OUT 128
#define NEG_SLOPE 0.2f

typedef short short8 __attribute__((ext_vector_type(8)));
typedef float f32x4 __attribute__((ext_vector_type(4)));

__device__ __forceinline__ unsigned short f2bf_rne(float f) {
  unsigned u = __float_as_uint(f);
  u += 0x7FFFu + ((u >> 16) & 1u);   // round-to-nearest-even
  return (unsigned short)(u >> 16);
}

__device__ __forceinline__ float bf_lo(unsigned u) { return __uint_as_float(u << 16); }
__device__ __forceinline__ float bf_hi(unsigned u) { return __uint_as_float(u & 0xFFFF0000u); }

// ---------------- setup: cast+transpose W -> Wt[n][k] bf16, deg=0 ----------------
__global__ __launch_bounds__(256) void setup_kernel(const float* __restrict__ W,
                                                    unsigned short* __restrict__ Wt,
                                                    int* __restrict__ deg, int N) {
  int idx = blockIdx.x * 256 + threadIdx.x;
  if (idx < F_IN * F_OUT) {
    int n = idx & 127, k = idx >> 7;
    Wt[(size_t)n * F_IN + k] = f2bf_rne(W[(size_t)k * F_OUT + n]);
  }
  if (idx < N) deg[idx] = 0;
}

// ---------------- GEMM: h = x @ W via bf16 MFMA + fused logits ----------------
// h stored bf16 in 4 feature panels: hbp[p][node][32], p = f/32 (3.2MB per panel
// -> fits one XCD's 4MB L2 for the panel-partitioned aggregate).
#define WT_STRIDE 72   // 64 + 8 pad (bf16 elems)

__global__ __launch_bounds__(256, 4) void gemm_kernel(const float* __restrict__ x,
                                                      const unsigned short* __restrict__ Wt,
                                                      const float* __restrict__ att_src,
                                                      const float* __restrict__ att_dst,
                                                      unsigned short* __restrict__ hbp,
                                                      float* __restrict__ a_src,
                                                      float* __restrict__ a_dst, int N) {
  __shared__ __attribute__((aligned(16))) unsigned short wt_l[128 * WT_STRIDE];
  const int tid  = threadIdx.x;
  const int lane = tid & 63;
  const int wv   = tid >> 6;
  const int q    = lane >> 4;
  const int l16  = lane & 15;
  const int m0   = blockIdx.x * 64;
  const int m    = m0 + wv * 16 + l16;
  const int mc   = (m < N) ? m : (N - 1);

  f32x4 acc[8];
#pragma unroll
  for (int i = 0; i < 8; ++i) acc[i] = (f32x4)(0.f);

  const int srow  = tid >> 1;
  const int shalf = tid & 1;

#pragma unroll 1
  for (int t = 0; t < 4; ++t) {
    {
      const unsigned short* g = Wt + (size_t)srow * F_IN + t * 64 + shalf * 32;
      unsigned short* l = wt_l + srow * WT_STRIDE + shalf * 32;
#pragma unroll
      for (int j = 0; j < 4; ++j)
        *(uint4*)(l + j * 8) = *(const uint4*)(g + j * 8);
    }
    __syncthreads();

#pragma unroll
    for (int s = 0; s < 2; ++s) {
      const int kg = t * 64 + s * 32 + q * 8;
      f32x4 a0 = *(const f32x4*)(x + (size_t)mc * F_IN + kg);
      f32x4 a1 = *(const f32x4*)(x + (size_t)mc * F_IN + kg + 4);
      short8 av;
      av[0] = (short)f2bf_rne(a0[0]); av[1] = (short)f2bf_rne(a0[1]);
      av[2] = (short)f2bf_rne(a0[2]); av[3] = (short)f2bf_rne(a0[3]);
      av[4] = (short)f2bf_rne(a1[0]); av[5] = (short)f2bf_rne(a1[1]);
      av[6] = (short)f2bf_rne(a1[2]); av[7] = (short)f2bf_rne(a1[3]);
#pragma unroll
      for (int nt = 0; nt < 8; ++nt) {
        short8 bv = *(const short8*)(wt_l + (nt * 16 + l16) * WT_STRIDE + s * 32 + q * 8);
        acc[nt] = __builtin_amdgcn_mfma_f32_16x16x32_bf16(av, bv, acc[nt], 0, 0, 0);
      }
    }
    __syncthreads();
  }

  float as_c[8], ad_c[8];
#pragma unroll
  for (int nt = 0; nt < 8; ++nt) {
    as_c[nt] = att_src[nt * 16 + l16];
    ad_c[nt] = att_dst[nt * 16 + l16];
  }
  float ps[4] = {0.f, 0.f, 0.f, 0.f}, pd[4] = {0.f, 0.f, 0.f, 0.f};
#pragma unroll
  for (int nt = 0; nt < 8; ++nt)
#pragma unroll
    for (int r = 0; r < 4; ++r) {
      ps[r] += acc[nt][r] * as_c[nt];
      pd[r] += acc[nt][r] * ad_c[nt];
    }
#pragma unroll
  for (int r = 0; r < 4; ++r) {
    int gm = m0 + wv * 16 + q * 4 + r;
    if (gm < N) {
      // feature f = nt*16+l16 -> panel nt>>1, offset (nt&1)*16 + l16
#pragma unroll
      for (int nt = 0; nt < 8; ++nt)
        hbp[((size_t)(nt >> 1) * N + gm) * 32 + (nt & 1) * 16 + l16] = f2bf_rne(acc[nt][r]);
    }
  }
#pragma unroll
  for (int r = 0; r < 4; ++r) {
#pragma unroll
    for (int off = 1; off <= 8; off <<= 1) {
      ps[r] += __shfl_xor(ps[r], off, 64);
      pd[r] += __shfl_xor(pd[r], off, 64);
    }
  }
  if (l16 == 0) {
#pragma unroll
    for (int r = 0; r < 4; ++r) {
      int gm = m0 + wv * 16 + q * 4 + r;
      if (gm < N) { a_src[gm] = ps[r]; a_dst[gm] = pd[r]; }
    }
  }
}

// ---------------- degree count + slot rank ----------------
__global__ void deg_rank_kernel(const int* __restrict__ ei, int* __restrict__ deg,
                                int* __restrict__ rank, int E) {
  int e = blockIdx.x * blockDim.x + threadIdx.x;
  if (e < E) rank[e] = atomicAdd(&deg[ei[E + e]], 1);
}

#define SCAN_CHUNK 2048

__global__ __launch_bounds__(256) void scan_chunk_kernel(const int* __restrict__ deg,
                                                         int* __restrict__ rowptr,
                                                         int* __restrict__ chunksum, int N) {
  __shared__ int wsum[4];
  const int tid = threadIdx.x, lane = tid & 63, wid = tid >> 6;
  const int base = blockIdx.x * SCAN_CHUNK + tid * 8;
  int v[8];
  int s = 0;
#pragma unroll
  for (int q = 0; q < 8; ++q) {
    int i = base + q;
    v[q] = (i < N) ? ((deg[i] + 1 + 3) & ~3) : 0;   // +1 self loop, pad row to x4
    s += v[q];
  }
  int incl = s;
#pragma unroll
  for (int off = 1; off < 64; off <<= 1) {
    int t = __shfl_up(incl, off, 64);
    if (lane >= off) incl += t;
  }
  if (lane == 63) wsum[wid] = incl;
  __syncthreads();
  int woff = 0;
#pragma unroll
  for (int w = 0; w < 4; ++w)
    if (w < wid) woff += wsum[w];
  int run = woff + incl - s;
#pragma unroll
  for (int q = 0; q < 8; ++q) {
    run += v[q];
    int i = base + q;
    if (i < N) rowptr[i + 1] = run;
  }
  if (tid == 0) chunksum[blockIdx.x] = wsum[0] + wsum[1] + wsum[2] + wsum[3];
}

__global__ void scan_fixup_kernel(int* __restrict__ rowptr, const int* __restrict__ chunksum,
                                  int N) {
  int i = blockIdx.x * blockDim.x + threadIdx.x;
  if (i == 0) rowptr[0] = 0;
  if (i < N) {
    int chunk = i / SCAN_CHUNK;
    int off = 0;
    for (int b = 0; b < chunk; ++b) off += chunksum[b];
    rowptr[i + 1] += off;
  }
}

__global__ void scatter_kernel(const int* __restrict__ ei, const int* __restrict__ rowptr,
                               const int* __restrict__ rank, const int* __restrict__ deg,
                               int* __restrict__ csr_src, int E, int N) {
  int idx = blockIdx.x * blockDim.x + threadIdx.x;
  if (idx < E) {
    int d = ei[E + idx];
    csr_src[rowptr[d] + rank[idx]] = ei[idx];
  } else if (idx < E + N) {
    int i = idx - E;
    csr_src[rowptr[i] + deg[i]] = i;   // self loop after real edges
  }
}

// ---------------- softmax stats: 16 lanes/node ----------------
__global__ __launch_bounds__(256) void stats_kernel(const int* __restrict__ rowptr,
                                                    const int* __restrict__ deg,
                                                    const int* __restrict__ csr_src,
                                                    const float* __restrict__ a_src,
                                                    const float* __restrict__ a_dst,
                                                    float* __restrict__ ew,
                                                    float* __restrict__ inv, int N) {
  int node = ((blockIdx.x * 256 + threadIdx.x) >> 4);
  int sub = threadIdx.x & 15;
  if (node >= N) return;
  int beg = rowptr[node], end = beg + deg[node] + 1;
  float ad = a_dst[node];
  float m = -INFINITY;
  for (int j = beg + sub; j < end; j += 16) {
    float e = a_src[csr_src[j]] + ad;
    e = (e > 0.f) ? e : NEG_SLOPE * e;
    ew[j] = e;
    m = fmaxf(m, e);
  }
#pragma unroll
  for (int off = 8; off >= 1; off >>= 1) m = fmaxf(m, __shfl_xor(m, off, 16));
  float s = 0.f;
  for (int j = beg + sub; j < end; j += 16) {
    float p = __expf(ew[j] - m);
    ew[j] = p;
    s += p;
  }
#pragma unroll
  for (int off = 8; off >= 1; off >>= 1) s += __shfl_xor(s, off, 16);
  if (sub == 0) inv[node] = 1.f / (s + 1e-16f);
}

// ---------------- panel-partitioned aggregate ----------------
// One wave per (node, panel). Panel chosen by (blockIdx%8)&3 so each XCD's L2
// (round-robin block placement) stays on one 3.2MB panel. 8 lanes/edge, uint2
// (4 features) per lane, 8 edges per gather instruction.
__global__ __launch_bounds__(256) void aggregate_kernel(const unsigned short* __restrict__ hbp,
                                                        const int* __restrict__ csr_src,
                                                        const float* __restrict__ ew,
                                                        const float* __restrict__ inv,
                                                        const int* __restrict__ rowptr,
                                                        const int* __restrict__ deg,
                                                        const float* __restrict__ bias,
                                                        float* __restrict__ out, int N) {
  const int b     = blockIdx.x;
  const int panel = (b & 7) & 3;
  const int idx   = (b >> 3) * 2 + ((b >> 2) & 1);   // per-panel block index
  const int wv    = threadIdx.x >> 6;
  const int node  = idx * 4 + wv;
  if (node >= N) return;
  const int lane  = threadIdx.x & 63;
  const int eslot = lane >> 3;      // 0..7: which edge in the batch
  const int fl    = lane & 7;       // features fl*4 .. fl*4+3 within panel

  const unsigned short* hp = hbp + (size_t)panel * N * 32;
  const int beg = rowptr[node];
  const int end = beg + deg[node] + 1;

  f32x4 acc = (f32x4)(0.f);
#pragma unroll 2
  for (int j = beg; j < end; j += 8) {
    int jj = j + eslot;
    bool act = jj < end;
    int   s = act ? csr_src[jj] : 0;
    float w = act ? ew[jj] : 0.f;
    uint2 hv = *(const uint2*)(hp + (size_t)s * 32 + fl * 4);
    acc[0] += w * bf_lo(hv.x);
    acc[1] += w * bf_hi(hv.x);
    acc[2] += w * bf_lo(hv.y);
    acc[3] += w * bf_hi(hv.y);
  }
  // reduce across the 8 edge slots (lane bits 3..5)
#pragma unroll
  for (int off = 8; off <= 32; off <<= 1)
#pragma unroll
    for (int k = 0; k < 4; ++k) acc[k] += __shfl_xor(acc[k], off, 64);

  if (eslot == 0) {
    float sc = inv[node];
    float4 bv = *(const float4*)(bias + panel * 32 + fl * 4);
    float4 o;
    o.x = acc[0] * sc + bv.x;
    o.y = acc[1] * sc + bv.y;
    o.z = acc[2] * sc + bv.z;
    o.w = acc[3] * sc + bv.w;
    *(float4*)&out[(size_t)node * F_OUT + panel * 32 + fl * 4] = o;
  }
}

// ---------------- launch ----------------
extern "C" void kernel_launch(void* const* d_in, const int* in_sizes, int n_in,
                              void* d_out, int out_size, void* d_ws, size_t ws_size,
                              hipStream_t stream) {
  const float* x     = (const float*)d_in[0];
  const int*   ei    = (const int*)d_in[1];
  const float* W     = (const float*)d_in[2];
  const float* att_s = (const float*)d_in[3];
  const float* att_d = (const float*)d_in[4];
  const float* bias  = (const float*)d_in[5];
  float* out = (float*)d_out;

  const int N = in_sizes[0] / F_IN;
  const int E = in_sizes[1] / 2;
  const int NB = (N + SCAN_CHUNK - 1) / SCAN_CHUNK;
  const size_t CSR_CAP = (size_t)E + 4 * (size_t)N + 8;

  char* p = (char*)d_ws;
  unsigned short* wt  = (unsigned short*)p; p += (size_t)F_IN * F_OUT * sizeof(unsigned short);
  unsigned short* hbp = (unsigned short*)p; p += (size_t)N * F_OUT * sizeof(unsigned short);
  float* a_src = (float*)p;  p += (size_t)N * sizeof(float);
  float* a_dst = (float*)p;  p += (size_t)N * sizeof(float);
  float* inv   = (float*)p;  p += (size_t)N * sizeof(float);
  int*   deg   = (int*)p;    p += (size_t)N * sizeof(int);
  int*   rowp  = (int*)p;    p += (size_t)(N + 1) * sizeof(int);
  int*   csum  = (int*)p;    p += (size_t)NB * sizeof(int);
  int*   rank  = (int*)p;    p += (size_t)E * sizeof(int);
  p = (char*)(((uintptr_t)p + 15) & ~(uintptr_t)15);
  int*   csr   = (int*)p;    p += CSR_CAP * sizeof(int);
  p = (char*)(((uintptr_t)p + 15) & ~(uintptr_t)15);
  float* ew    = (float*)p;  p += CSR_CAP * sizeof(float);

  int setup_n = (F_IN * F_OUT > N) ? F_IN * F_OUT : N;
  setup_kernel<<<(setup_n + 255) / 256, 256, 0, stream>>>(W, wt, deg, N);
  gemm_kernel<<<(N + 63) / 64, 256, 0, stream>>>(x, wt, att_s, att_d, hbp, a_src, a_dst, N);
  deg_rank_kernel<<<(E + 255) / 256, 256, 0, stream>>>(ei, deg, rank, E);
  scan_chunk_kernel<<<NB, 256, 0, stream>>>(deg, rowp, csum, N);
  scan_fixup_kernel<<<(N + 255) / 256, 256, 0, stream>>>(rowp, csum, N);
  scatter_kernel<<<(E + N + 255) / 256, 256, 0, stream>>>(ei, rowp, rank, deg, csr, E, N);
  stats_kernel<<<((size_t)N * 16 + 255) / 256, 256, 0, stream>>>(rowp, deg, csr, a_src, a_dst, ew, inv, N);
  // blocks: 8 per pair-of-panel-indices; covers idx in [0, ceil(N/4)) for all 4 panels
  int npp = (N + 3) / 4;
  int agg_blocks = 8 * ((npp + 1) / 2);
  aggregate_kernel<<<agg_blocks, 256, 0, stream>>>(hbp, csr, ew, inv, rowp, deg, bias, out, N);
}

// Round 9
// 218.425 us; speedup vs baseline: 1.1661x; 1.1661x over previous
//
#include <hip/hip_runtime.h>
#include <cstdint>
#include <cstddef>

#define F_IN 256
#define F_OUT 128
#define NEG_SLOPE 0.2f

typedef short short8 __attribute__((ext_vector_type(8)));
typedef float f32x4 __attribute__((ext_vector_type(4)));

__device__ __forceinline__ unsigned short f2bf_rne(float f) {
  unsigned u = __float_as_uint(f);
  u += 0x7FFFu + ((u >> 16) & 1u);   // round-to-nearest-even
  return (unsigned short)(u >> 16);
}

__device__ __forceinline__ float bf_lo(unsigned u) { return __uint_as_float(u << 16); }
__device__ __forceinline__ float bf_hi(unsigned u) { return __uint_as_float(u & 0xFFFF0000u); }

// ---------------- setup: cast+transpose W -> Wt[n][k] bf16 ----------------
__global__ __launch_bounds__(256) void setup_kernel(const float* __restrict__ W,
                                                    unsigned short* __restrict__ Wt) {
  int idx = blockIdx.x * 256 + threadIdx.x;   // 32768 total
  int n = idx & 127, k = idx >> 7;
  Wt[(size_t)n * F_IN + k] = f2bf_rne(W[(size_t)k * F_OUT + n]);
}

// ---------------- GEMM: h = x @ W via bf16 MFMA + fused logits; h stored bf16 flat ----------------
#define WT_STRIDE 72   // 64 + 8 pad (bf16 elems)

__global__ __launch_bounds__(256, 4) void gemm_kernel(const float* __restrict__ x,
                                                      const unsigned short* __restrict__ Wt,
                                                      const float* __restrict__ att_src,
                                                      const float* __restrict__ att_dst,
                                                      unsigned short* __restrict__ hb,
                                                      float* __restrict__ a_src,
                                                      float* __restrict__ a_dst, int N) {
  __shared__ __attribute__((aligned(16))) unsigned short wt_l[128 * WT_STRIDE];
  const int tid  = threadIdx.x;
  const int lane = tid & 63;
  const int wv   = tid >> 6;
  const int q    = lane >> 4;
  const int l16  = lane & 15;
  const int m0   = blockIdx.x * 64;
  const int m    = m0 + wv * 16 + l16;
  const int mc   = (m < N) ? m : (N - 1);

  f32x4 acc[8];
#pragma unroll
  for (int i = 0; i < 8; ++i) acc[i] = (f32x4)(0.f);

  const int srow  = tid >> 1;
  const int shalf = tid & 1;

#pragma unroll 1
  for (int t = 0; t < 4; ++t) {
    {
      const unsigned short* g = Wt + (size_t)srow * F_IN + t * 64 + shalf * 32;
      unsigned short* l = wt_l + srow * WT_STRIDE + shalf * 32;
#pragma unroll
      for (int j = 0; j < 4; ++j)
        *(uint4*)(l + j * 8) = *(const uint4*)(g + j * 8);
    }
    __syncthreads();

#pragma unroll
    for (int s = 0; s < 2; ++s) {
      const int kg = t * 64 + s * 32 + q * 8;
      f32x4 a0 = *(const f32x4*)(x + (size_t)mc * F_IN + kg);
      f32x4 a1 = *(const f32x4*)(x + (size_t)mc * F_IN + kg + 4);
      short8 av;
      av[0] = (short)f2bf_rne(a0[0]); av[1] = (short)f2bf_rne(a0[1]);
      av[2] = (short)f2bf_rne(a0[2]); av[3] = (short)f2bf_rne(a0[3]);
      av[4] = (short)f2bf_rne(a1[0]); av[5] = (short)f2bf_rne(a1[1]);
      av[6] = (short)f2bf_rne(a1[2]); av[7] = (short)f2bf_rne(a1[3]);
#pragma unroll
      for (int nt = 0; nt < 8; ++nt) {
        short8 bv = *(const short8*)(wt_l + (nt * 16 + l16) * WT_STRIDE + s * 32 + q * 8);
        acc[nt] = __builtin_amdgcn_mfma_f32_16x16x32_bf16(av, bv, acc[nt], 0, 0, 0);
      }
    }
    __syncthreads();
  }

  float as_c[8], ad_c[8];
#pragma unroll
  for (int nt = 0; nt < 8; ++nt) {
    as_c[nt] = att_src[nt * 16 + l16];
    ad_c[nt] = att_dst[nt * 16 + l16];
  }
  float ps[4] = {0.f, 0.f, 0.f, 0.f}, pd[4] = {0.f, 0.f, 0.f, 0.f};
#pragma unroll
  for (int nt = 0; nt < 8; ++nt)
#pragma unroll
    for (int r = 0; r < 4; ++r) {
      ps[r] += acc[nt][r] * as_c[nt];
      pd[r] += acc[nt][r] * ad_c[nt];
    }
#pragma unroll
  for (int r = 0; r < 4; ++r) {
    int gm = m0 + wv * 16 + q * 4 + r;
    if (gm < N) {
#pragma unroll
      for (int nt = 0; nt < 8; ++nt)
        hb[(size_t)gm * F_OUT + nt * 16 + l16] = f2bf_rne(acc[nt][r]);
    }
  }
#pragma unroll
  for (int r = 0; r < 4; ++r) {
#pragma unroll
    for (int off = 1; off <= 8; off <<= 1) {
      ps[r] += __shfl_xor(ps[r], off, 64);
      pd[r] += __shfl_xor(pd[r], off, 64);
    }
  }
  if (l16 == 0) {
#pragma unroll
    for (int r = 0; r < 4; ++r) {
      int gm = m0 + wv * 16 + q * 4 + r;
      if (gm < N) { a_src[gm] = ps[r]; a_dst[gm] = pd[r]; }
    }
  }
}

// ---------------- degree count + slot rank ----------------
__global__ void deg_rank_kernel(const int* __restrict__ ei, int* __restrict__ deg,
                                int* __restrict__ rank, int E) {
  int e = blockIdx.x * blockDim.x + threadIdx.x;
  if (e < E) rank[e] = atomicAdd(&deg[ei[E + e]], 1);
}

#define SCAN_CHUNK 2048   // 2^11; chunk(i) = i >> 11

// exclusive within-chunk scan of padded row sizes; last-finishing block
// computes the chunk-offset prefix (device-scope atomics + fences, XCD-safe)
__global__ __launch_bounds__(256) void scan_chunk_kernel(const int* __restrict__ deg,
                                                         int* __restrict__ rowptr,
                                                         int* __restrict__ chunksum,
                                                         int* __restrict__ chunkoff,
                                                         int* __restrict__ ctr, int N) {
  __shared__ int wsum[4];
  __shared__ int lastFlag;
  const int tid = threadIdx.x, lane = tid & 63, wid = tid >> 6;
  const int base = blockIdx.x * SCAN_CHUNK + tid * 8;
  int v[8];
  int s = 0;
#pragma unroll
  for (int q = 0; q < 8; ++q) {
    int i = base + q;
    v[q] = (i < N) ? ((deg[i] + 4) & ~3) : 0;   // deg + self loop, padded to x4
    s += v[q];
  }
  int incl = s;
#pragma unroll
  for (int off = 1; off < 64; off <<= 1) {
    int t = __shfl_up(incl, off, 64);
    if (lane >= off) incl += t;
  }
  if (lane == 63) wsum[wid] = incl;
  __syncthreads();
  int woff = 0;
#pragma unroll
  for (int w = 0; w < 4; ++w)
    if (w < wid) woff += wsum[w];
  int run = woff + incl - s;          // exclusive prefix of this thread's first elem
#pragma unroll
  for (int q = 0; q < 8; ++q) {
    int i = base + q;
    if (i < N) rowptr[i] = run;       // exclusive, chunk-local
    run += v[q];
  }
  if (tid == 0) {
    int tot = wsum[0] + wsum[1] + wsum[2] + wsum[3];
    atomicExch(&chunksum[blockIdx.x], tot);
    __threadfence();
    int t = atomicAdd(ctr, 1);
    lastFlag = (t == (int)gridDim.x - 1);
  }
  __syncthreads();
  if (lastFlag && tid == 0) {
    __threadfence();
    int run2 = 0;
    for (int b = 0; b < (int)gridDim.x; ++b) {
      chunkoff[b] = run2;
      run2 += atomicAdd(&chunksum[b], 0);   // device-scope read
    }
  }
}

// atomic-free scatter; final position = chunk-local rowptr + chunkoff
__global__ void scatter_kernel(const int* __restrict__ ei, const int* __restrict__ rowptr,
                               const int* __restrict__ chunkoff, const int* __restrict__ rank,
                               const int* __restrict__ deg, int* __restrict__ csr_src,
                               int E, int N) {
  int idx = blockIdx.x * blockDim.x + threadIdx.x;
  if (idx < E) {
    int d = ei[E + idx];
    csr_src[rowptr[d] + chunkoff[d >> 11] + rank[idx]] = ei[idx];
  } else if (idx < E + N) {
    int i = idx - E;
    csr_src[rowptr[i] + chunkoff[i >> 11] + deg[i]] = i;   // self loop after real edges
  }
}

// ---------------- fused softmax + aggregate: one wave per node ----------------
// Pass A: gather a_src (L2-resident), max + exp-sum, weights cached in LDS
// (64 slots/wave; overflow recomputed). Pass B: r7 gather core, w from LDS.
__global__ __launch_bounds__(256) void aggregate_kernel(const unsigned short* __restrict__ hb,
                                                        const int* __restrict__ csr_src,
                                                        const float* __restrict__ a_src,
                                                        const float* __restrict__ a_dst,
                                                        const int* __restrict__ rowptr,
                                                        const int* __restrict__ chunkoff,
                                                        const int* __restrict__ deg,
                                                        const float* __restrict__ bias,
                                                        float* __restrict__ out, int N) {
  __shared__ float ldsW[4 * 64];
  int node = (blockIdx.x * 256 + threadIdx.x) >> 6;
  if (node >= N) return;                       // no __syncthreads below (wave-local LDS only)
  const int lane = threadIdx.x & 63;
  float* wbuf = ldsW + (threadIdx.x >> 6) * 64;

  const int dg  = deg[node];
  const int beg = rowptr[node] + chunkoff[node >> 11];   // multiple of 4
  const int end = beg + dg + 1;
  const float ad = a_dst[node];

  // ---- pass A1: logits + max ----
  float mx = -INFINITY;
  for (int j = beg + lane; j < end; j += 64) {
    float e = a_src[csr_src[j]] + ad;
    e = (e > 0.f) ? e : NEG_SLOPE * e;
    int slot = j - beg;
    if (slot < 64) wbuf[slot] = e;
    mx = fmaxf(mx, e);
  }
#pragma unroll
  for (int off = 32; off >= 1; off >>= 1) mx = fmaxf(mx, __shfl_xor(mx, off, 64));

  // ---- pass A2: exp + sum ----
  float s = 0.f;
  for (int j = beg + lane; j < end; j += 64) {
    int slot = j - beg;
    float e;
    if (slot < 64) e = wbuf[slot];
    else {
      e = a_src[csr_src[j]] + ad;
      e = (e > 0.f) ? e : NEG_SLOPE * e;
    }
    float pz = __expf(e - mx);
    if (slot < 64) wbuf[slot] = pz;
    s += pz;
  }
#pragma unroll
  for (int off = 32; off >= 1; off >>= 1) s += __shfl_xor(s, off, 64);
  const float invs = 1.f / (s + 1e-16f);

  // ---- pass B: weighted gather (r7 core) ----
  const int half = lane >> 5;   // edge parity
  const int l32  = lane & 31;   // features l32*4 .. l32*4+3
  f32x4 acc = (f32x4)(0.f);

  auto wof = [&](int slot, int sidx) -> float {
    if (slot < 64) return wbuf[slot];
    float e = a_src[sidx] + ad;
    e = (e > 0.f) ? e : NEG_SLOPE * e;
    return __expf(e - mx);
  };

  int j = beg;
  for (; j + 8 <= end; j += 8) {
    int4 c0 = *(const int4*)(csr_src + j);
    int4 c1 = *(const int4*)(csr_src + j + 4);
    int cs[8] = {c0.x, c0.y, c0.z, c0.w, c1.x, c1.y, c1.z, c1.w};
#pragma unroll
    for (int u = 0; u < 4; ++u) {
      int   sidx = cs[2 * u + half];
      float w    = wof(j + 2 * u + half - beg, sidx);
      uint2 hv = *(const uint2*)(hb + (size_t)sidx * F_OUT + l32 * 4);
      acc[0] += w * bf_lo(hv.x);
      acc[1] += w * bf_hi(hv.x);
      acc[2] += w * bf_lo(hv.y);
      acc[3] += w * bf_hi(hv.y);
    }
  }
  for (; j + 2 <= end; j += 2) {
    int   sidx = csr_src[j + half];
    float w    = wof(j + half - beg, sidx);
    uint2 hv = *(const uint2*)(hb + (size_t)sidx * F_OUT + l32 * 4);
    acc[0] += w * bf_lo(hv.x);
    acc[1] += w * bf_hi(hv.x);
    acc[2] += w * bf_lo(hv.y);
    acc[3] += w * bf_hi(hv.y);
  }
  if (j < end && half == 0) {
    int   sidx = csr_src[j];
    float w    = wof(j - beg, sidx);
    uint2 hv = *(const uint2*)(hb + (size_t)sidx * F_OUT + l32 * 4);
    acc[0] += w * bf_lo(hv.x);
    acc[1] += w * bf_hi(hv.x);
    acc[2] += w * bf_lo(hv.y);
    acc[3] += w * bf_hi(hv.y);
  }
#pragma unroll
  for (int k = 0; k < 4; ++k) acc[k] += __shfl_xor(acc[k], 32, 64);

  if (half == 0) {
    float4 bv = *(const float4*)(bias + l32 * 4);
    float4 o;
    o.x = acc[0] * invs + bv.x;
    o.y = acc[1] * invs + bv.y;
    o.z = acc[2] * invs + bv.z;
    o.w = acc[3] * invs + bv.w;
    *(float4*)&out[(size_t)node * F_OUT + l32 * 4] = o;
  }
}

// ---------------- launch ----------------
extern "C" void kernel_launch(void* const* d_in, const int* in_sizes, int n_in,
                              void* d_out, int out_size, void* d_ws, size_t ws_size,
                              hipStream_t stream) {
  const float* x     = (const float*)d_in[0];
  const int*   ei    = (const int*)d_in[1];
  const float* W     = (const float*)d_in[2];
  const float* att_s = (const float*)d_in[3];
  const float* att_d = (const float*)d_in[4];
  const float* bias  = (const float*)d_in[5];
  float* out = (float*)d_out;

  const int N = in_sizes[0] / F_IN;
  const int E = in_sizes[1] / 2;
  const int NB = (N + SCAN_CHUNK - 1) / SCAN_CHUNK;
  const size_t CSR_CAP = (size_t)E + 4 * (size_t)N + 8;

  char* p = (char*)d_ws;
  unsigned short* wt = (unsigned short*)p; p += (size_t)F_IN * F_OUT * sizeof(unsigned short);
  unsigned short* hb = (unsigned short*)p; p += (size_t)N * F_OUT * sizeof(unsigned short);
  float* a_src = (float*)p;  p += (size_t)N * sizeof(float);
  float* a_dst = (float*)p;  p += (size_t)N * sizeof(float);
  int*   deg   = (int*)p;    p += (size_t)N * sizeof(int);
  int*   ctr   = (int*)p;    p += sizeof(int);                 // adjacent to deg (one memset)
  int*   rowp  = (int*)p;    p += (size_t)N * sizeof(int);
  int*   csum  = (int*)p;    p += (size_t)NB * sizeof(int);
  int*   coff  = (int*)p;    p += (size_t)NB * sizeof(int);
  int*   rank  = (int*)p;    p += (size_t)E * sizeof(int);
  p = (char*)(((uintptr_t)p + 15) & ~(uintptr_t)15);
  int*   csr   = (int*)p;    p += CSR_CAP * sizeof(int);

  hipMemsetAsync(deg, 0, (size_t)(N + 1) * sizeof(int), stream);   // deg + ctr
  setup_kernel<<<(F_IN * F_OUT) / 256, 256, 0, stream>>>(W, wt);
  gemm_kernel<<<(N + 63) / 64, 256, 0, stream>>>(x, wt, att_s, att_d, hb, a_src, a_dst, N);
  deg_rank_kernel<<<(E + 255) / 256, 256, 0, stream>>>(ei, deg, rank, E);
  scan_chunk_kernel<<<NB, 256, 0, stream>>>(deg, rowp, csum, coff, ctr, N);
  scatter_kernel<<<(E + N + 255) / 256, 256, 0, stream>>>(ei, rowp, coff, rank, deg, csr, E, N);
  aggregate_kernel<<<((size_t)N * 64 + 255) / 256, 256, 0, stream>>>(hb, csr, a_src, a_dst, rowp, coff, deg, bias, out, N);
}